// Round 2
// baseline (215.814 us; speedup 1.0000x reference)
//
#include <hip/hip_runtime.h>
#include <math.h>

// CapsuleLayer dynamic routing — multi-kernel, batch-shared W, i-split.
// B=256, IN=1152, K=8, J=10, D=16, 3 routing passes.
//
// Algebra: logits at pass t are (sum of previous outputs v) . u_hat, so we
// keep only vdot[b][j][d]; pass 0 has c = 0.1 exactly (softmax of zeros).
//
// Kernel A (per pass): grid (24 i-slices x 32 b-groups), block 512 =
// 16 i-groups x 8 batches x 4 d-quads. Recomputes u_hat on the fly
// (float4 W loads, 8-way batch reuse via L1), accumulates partial
// s[b][j][d] for its i-slice, block-reduces, writes to ws.
// Kernel B (per pass): reduces 24 partials, squash, updates vdot / out.

typedef float f32x4 __attribute__((ext_vector_type(4)));

#define B_TOT 256
#define IN_CAPS 1152
#define IN_DIM 8
#define OUT_CAPS 10
#define OUT_DIM 16
#define JD (OUT_CAPS * OUT_DIM)        // 160

#define NB 8                            // batches per block
#define NG 16                           // i-groups per block
#define A_THREADS 512                   // NG * NB * 4
#define ISLICES 24
#define I_PER_BLK (IN_CAPS / ISLICES)   // 48
#define A_ITERS (I_PER_BLK / NG)        // 3
#define XPAD_F (I_PER_BLK * IN_DIM + 4) // 388 floats (bank-conflict pad)
#define NWAVES (A_THREADS / 64)         // 8

template<bool FIRST>
__global__ __launch_bounds__(A_THREADS)
void caps_partial_kernel(const float* __restrict__ x,
                         const float* __restrict__ W,
                         const float* __restrict__ vdot,
                         float* __restrict__ s_part) {
    __shared__ __align__(16) float xs[NB * XPAD_F];                 // 12416 B
    __shared__ __align__(16) float sred[NWAVES * NB * JD];          // 40960 B

    const int tid  = threadIdx.x;
    const int d4   = tid & 3;           // d-quad index (d = d4*4..d4*4+3)
    const int bsub = (tid >> 2) & 7;    // batch within block
    const int g    = tid >> 5;          // i-group 0..15
    const int is   = blockIdx.x;        // i-slice 0..23
    const int bg   = blockIdx.y;        // b-group 0..31
    const int b    = bg * NB + bsub;
    const int i0   = is * I_PER_BLK;

    // ---- stage x[bg*8 .. +7, i0 .. i0+47, :] into LDS (padded) ----
    {
        const int F4_PER_B = I_PER_BLK * IN_DIM / 4;   // 96 float4 per batch
        for (int t = tid; t < NB * F4_PER_B; t += A_THREADS) {
            const int bl = t / F4_PER_B, f = t % F4_PER_B;
            f32x4 v = *(const f32x4*)(x + ((size_t)(bg * NB + bl) * IN_CAPS + i0) * IN_DIM + f * 4);
            *(f32x4*)(xs + bl * XPAD_F + f * 4) = v;
        }
    }

    // running-output dot vector for this (b, d-quad)
    f32x4 vd[OUT_CAPS];
    if (!FIRST) {
        #pragma unroll
        for (int j = 0; j < OUT_CAPS; ++j)
            vd[j] = *(const f32x4*)(vdot + (size_t)b * JD + j * OUT_DIM + d4 * 4);
    }
    __syncthreads();

    f32x4 s[OUT_CAPS];
    #pragma unroll
    for (int j = 0; j < OUT_CAPS; ++j) s[j] = (f32x4){0.f, 0.f, 0.f, 0.f};

    for (int it = 0; it < A_ITERS; ++it) {
        const int il = it * NG + g;
        const int i  = i0 + il;

        // x[b, i, 0..7] from LDS (broadcast across d4)
        const f32x4* xr = (const f32x4*)(xs + bsub * XPAD_F + il * IN_DIM);
        const f32x4 xa = xr[0], xb2 = xr[1];
        const float xk[8] = {xa.x, xa.y, xa.z, xa.w, xb2.x, xb2.y, xb2.z, xb2.w};

        // u_hat[i, j, d-quad] : float4 W loads, contiguous in d
        const f32x4* wp = (const f32x4*)(W + (size_t)i * (OUT_CAPS * IN_DIM * OUT_DIM)) + d4;
        f32x4 u[OUT_CAPS];
        #pragma unroll
        for (int j = 0; j < OUT_CAPS; ++j) {
            f32x4 acc = (f32x4){0.f, 0.f, 0.f, 0.f};
            #pragma unroll
            for (int k = 0; k < IN_DIM; ++k)
                acc += xk[k] * wp[j * 32 + k * 4];
            u[j] = acc;
        }

        if (FIRST) {
            #pragma unroll
            for (int j = 0; j < OUT_CAPS; ++j) s[j] += 0.1f * u[j];
        } else {
            // logit[j] = sum_d vdot . u  (local 4-dot + 2-step quad butterfly)
            float lt[OUT_CAPS];
            #pragma unroll
            for (int j = 0; j < OUT_CAPS; ++j) {
                const f32x4 p = vd[j] * u[j];
                float t = (p.x + p.y) + (p.z + p.w);
                t += __shfl_xor(t, 1);
                t += __shfl_xor(t, 2);
                lt[j] = t;
            }
            float m = lt[0];
            #pragma unroll
            for (int j = 1; j < OUT_CAPS; ++j) m = fmaxf(m, lt[j]);
            float Z = 0.f;
            #pragma unroll
            for (int j = 0; j < OUT_CAPS; ++j) { lt[j] = __expf(lt[j] - m); Z += lt[j]; }
            const float invZ = 1.0f / Z;
            #pragma unroll
            for (int j = 0; j < OUT_CAPS; ++j) s[j] += (lt[j] * invZ) * u[j];
        }
    }

    // ---- reduce the two i-groups sharing each wave (lane bit 5) ----
    #pragma unroll
    for (int j = 0; j < OUT_CAPS; ++j) {
        s[j].x += __shfl_xor(s[j].x, 32);
        s[j].y += __shfl_xor(s[j].y, 32);
        s[j].z += __shfl_xor(s[j].z, 32);
        s[j].w += __shfl_xor(s[j].w, 32);
    }
    const int lane = tid & 63;
    const int wv   = tid >> 6;
    if (lane < 32) {
        f32x4* sr4 = (f32x4*)sred;
        #pragma unroll
        for (int j = 0; j < OUT_CAPS; ++j)
            sr4[wv * (NB * JD / 4) + bsub * (JD / 4) + j * 4 + d4] = s[j];
    }
    __syncthreads();

    // ---- sum the 8 wave-partials, write block partial to ws ----
    for (int t = tid; t < NB * JD; t += A_THREADS) {
        float acc = 0.f;
        #pragma unroll
        for (int w = 0; w < NWAVES; ++w) acc += sred[w * (NB * JD) + t];
        s_part[((size_t)is * B_TOT + bg * NB + t / JD) * JD + (t % JD)] = acc;
    }
}

// ---- reduce partials + squash + vdot / out ----
#define B_THREADS 256
template<int PASS>
__global__ __launch_bounds__(B_THREADS)
void caps_squash_kernel(const float* __restrict__ s_part,
                        float* __restrict__ vdot,
                        float* __restrict__ out) {
    const int elem = blockIdx.x * B_THREADS + threadIdx.x;   // < 256*160
    float s = 0.f;
    #pragma unroll
    for (int p = 0; p < ISLICES; ++p)
        s += s_part[(size_t)p * (B_TOT * JD) + elem];

    // squash: norm over d (16-lane group; elem%16 = d, groups lane-aligned)
    float t = s * s;
    t += __shfl_xor(t, 1);
    t += __shfl_xor(t, 2);
    t += __shfl_xor(t, 4);
    t += __shfl_xor(t, 8);
    const float scale = t / (1.0f + t) / sqrtf(t + 1e-7f);
    const float v = scale * s;

    if (PASS == 0)      vdot[elem] = v;
    else if (PASS == 1) vdot[elem] += v;
    else                out[elem] = v;
}

// =====================================================================
// Fallback: round-1 fully fused kernel (used only if ws_size too small)
// =====================================================================
#define FB_NGROUPS 32
#define FB_THREADS (FB_NGROUPS * OUT_DIM)
#define FB_ITERS (IN_CAPS / FB_NGROUPS)

__global__ __launch_bounds__(FB_THREADS)
void caps_routing_kernel(const float* __restrict__ x,
                         const float* __restrict__ W,
                         float* __restrict__ out) {
    __shared__ __align__(16) float xsf[IN_CAPS * IN_DIM];
    __shared__ float sredf[FB_NGROUPS * JD];
    __shared__ float vdot_lds[JD];

    const int b = blockIdx.x, tid = threadIdx.x;
    const int g = tid >> 4, d = tid & 15;
    {
        const float4* xg = reinterpret_cast<const float4*>(x + (size_t)b * IN_CAPS * IN_DIM);
        float4* xl = reinterpret_cast<float4*>(xsf);
        for (int t = tid; t < IN_CAPS * IN_DIM / 4; t += FB_THREADS) xl[t] = xg[t];
    }
    __syncthreads();
    for (int pass = 0; pass < 3; ++pass) {
        float vdot_reg[OUT_CAPS];
        if (pass > 0) {
            #pragma unroll
            for (int j = 0; j < OUT_CAPS; ++j) vdot_reg[j] = vdot_lds[j * OUT_DIM + d];
        }
        float s_loc[OUT_CAPS];
        #pragma unroll
        for (int j = 0; j < OUT_CAPS; ++j) s_loc[j] = 0.f;
        for (int it = 0; it < FB_ITERS; ++it) {
            const int i = it * FB_NGROUPS + g;
            float xk[IN_DIM];
            {
                const float4* xr = reinterpret_cast<const float4*>(xsf + i * IN_DIM);
                float4 a0 = xr[0], a1 = xr[1];
                xk[0]=a0.x; xk[1]=a0.y; xk[2]=a0.z; xk[3]=a0.w;
                xk[4]=a1.x; xk[5]=a1.y; xk[6]=a1.z; xk[7]=a1.w;
            }
            const float* wpf = W + (size_t)i * (OUT_CAPS * IN_DIM * OUT_DIM) + d;
            float u[OUT_CAPS];
            #pragma unroll
            for (int j = 0; j < OUT_CAPS; ++j) {
                float acc = 0.f;
                #pragma unroll
                for (int k = 0; k < IN_DIM; ++k)
                    acc = fmaf(xk[k], wpf[j * (IN_DIM * OUT_DIM) + k * OUT_DIM], acc);
                u[j] = acc;
            }
            if (pass == 0) {
                #pragma unroll
                for (int j = 0; j < OUT_CAPS; ++j) s_loc[j] = fmaf(0.1f, u[j], s_loc[j]);
            } else {
                float logit[OUT_CAPS];
                #pragma unroll
                for (int j = 0; j < OUT_CAPS; ++j) {
                    float t2 = vdot_reg[j] * u[j];
                    t2 += __shfl_xor(t2, 1); t2 += __shfl_xor(t2, 2);
                    t2 += __shfl_xor(t2, 4); t2 += __shfl_xor(t2, 8);
                    logit[j] = t2;
                }
                float m = logit[0];
                #pragma unroll
                for (int j = 1; j < OUT_CAPS; ++j) m = fmaxf(m, logit[j]);
                float Z = 0.f, e[OUT_CAPS];
                #pragma unroll
                for (int j = 0; j < OUT_CAPS; ++j) { e[j] = expf(logit[j] - m); Z += e[j]; }
                const float invZ = 1.0f / Z;
                #pragma unroll
                for (int j = 0; j < OUT_CAPS; ++j) s_loc[j] = fmaf(e[j] * invZ, u[j], s_loc[j]);
            }
        }
        #pragma unroll
        for (int j = 0; j < OUT_CAPS; ++j) sredf[g * JD + j * OUT_DIM + d] = s_loc[j];
        __syncthreads();
        if (tid < JD) {
            float sv = 0.f;
            #pragma unroll 8
            for (int gg = 0; gg < FB_NGROUPS; ++gg) sv += sredf[gg * JD + tid];
            float t2 = sv * sv;
            t2 += __shfl_xor(t2, 1); t2 += __shfl_xor(t2, 2);
            t2 += __shfl_xor(t2, 4); t2 += __shfl_xor(t2, 8);
            const float scale = t2 / (1.0f + t2) / sqrtf(t2 + 1e-7f);
            const float v = scale * sv;
            if (pass == 2) out[(size_t)b * JD + tid] = v;
            else vdot_lds[tid] = (pass == 0) ? v : (vdot_lds[tid] + v);
        }
        __syncthreads();
    }
}

extern "C" void kernel_launch(void* const* d_in, const int* in_sizes, int n_in,
                              void* d_out, int out_size, void* d_ws, size_t ws_size,
                              hipStream_t stream) {
    const float* x = (const float*)d_in[0];
    const float* W = (const float*)d_in[1];
    float* out = (float*)d_out;

    const size_t spart_elems = (size_t)ISLICES * B_TOT * JD;      // 983,040
    const size_t need = (spart_elems + (size_t)B_TOT * JD) * sizeof(float);  // ~4.1 MB

    if (ws_size >= need) {
        float* s_part = (float*)d_ws;
        float* vdot   = (float*)d_ws + spart_elems;
        const dim3 gA(ISLICES, B_TOT / NB), bA(A_THREADS);
        const int gB = (B_TOT * JD) / B_THREADS;   // 160

        caps_partial_kernel<true ><<<gA, bA, 0, stream>>>(x, W, nullptr, s_part);
        caps_squash_kernel<0><<<gB, B_THREADS, 0, stream>>>(s_part, vdot, out);
        caps_partial_kernel<false><<<gA, bA, 0, stream>>>(x, W, vdot, s_part);
        caps_squash_kernel<1><<<gB, B_THREADS, 0, stream>>>(s_part, vdot, out);
        caps_partial_kernel<false><<<gA, bA, 0, stream>>>(x, W, vdot, s_part);
        caps_squash_kernel<2><<<gB, B_THREADS, 0, stream>>>(s_part, vdot, out);
    } else {
        caps_routing_kernel<<<B_TOT, FB_THREADS, 0, stream>>>(x, W, out);
    }
}

// Round 3
// 101.705 us; speedup vs baseline: 2.1220x; 2.1220x over previous
//
#include <hip/hip_runtime.h>
#include <math.h>

// CapsuleLayer dynamic routing — W-in-LDS, i-sliced, no atomics.
// B=256, IN=1152, K=8, J=10, D=16, 3 routing passes.
//
// Algebra: b_t[i,j] = (sum_{t'<t} v_{t'})[j,:].u_hat[i,j,:] (b starts at 0),
// so only vdot = running sum of outputs is kept; pass 0 has c = 0.1 exactly.
//
// caps_main<PASS>: grid (16 i-slices x 16 b-groups), 512 thr.
//   Block covers 72 i x 16 b. W chunked into LDS (3 x 24 i = 122.9 KB),
//   x slice staged once (37.1 KB). Thread = (dh quad, jq half, bl x bt=2
//   batches, ig of 8 i-groups): 40 W ds_read_b128 -> 320 FMAs per i.
//   ig-partials reduced via LDS; block stores one contiguous 2560-float
//   partial to s_part[is]. Deterministic (no atomics).
// caps_squash<PASS>: reduce 16 slabs, squash, update vdot / out.

typedef float f32x4 __attribute__((ext_vector_type(4)));

#define B_TOT 256
#define IN_CAPS 1152
#define OUT_CAPS 10
#define OUT_DIM 16
#define JD 160

#define NSLICE 16          // i slices
#define IPB 72             // i per block
#define NBG 16             // batch groups
#define BPB 16             // batches per block
#define CHUNK 24           // i per W chunk (3 chunks)
#define XROW 580           // padded floats per b row (72*8=576 +4)
#define REDSTRIDE 2564     // per-ig stride in reduce scratch (2560 + 4)

#define SPART_ELEMS ((size_t)NSLICE * B_TOT * JD)   // 655360
#define VDOT_ELEMS  ((size_t)B_TOT * JD)            // 40960

template<int PASS>
__global__ __launch_bounds__(512, 1)
void caps_main(const float* __restrict__ x,
               const float* __restrict__ W,
               const float* __restrict__ vdot,
               float* __restrict__ s_part) {
    __shared__ __align__(16) float xs[BPB * XROW];      // 37,120 B
    __shared__ __align__(16) float wl[CHUNK * 1280];    // 122,880 B

    const int tid = threadIdx.x;
    const int dh  = tid & 3;           // d-quad
    const int jq  = (tid >> 2) & 1;    // j half (j = jq*5 + jj)
    const int bl  = (tid >> 3) & 7;    // batch slot (2 batches each)
    const int ig  = tid >> 6;          // i-group 0..7 (== wave id)
    const int is  = blockIdx.x;        // i slice
    const int bg  = blockIdx.y;        // batch group
    const int bL0 = bl * 2;            // local batch 0 (and +1)

    // ---- stage x[bg*16 .. +16, is*72 .. +72, :] into LDS (padded rows) ----
    for (int t = tid; t < BPB * 144; t += 512) {
        const int r = t / 144, c = t % 144;
        f32x4 v = *(const f32x4*)(x + (size_t)(bg * BPB + r) * (IN_CAPS * 8)
                                    + (size_t)is * (IPB * 8) + c * 4);
        *(f32x4*)(xs + r * XROW + c * 4) = v;
    }

    // ---- vdot fragments (i-invariant), PASS >= 1 ----
    f32x4 vd[2][5];
    if (PASS > 0) {
        #pragma unroll
        for (int bt = 0; bt < 2; ++bt)
            #pragma unroll
            for (int jj = 0; jj < 5; ++jj)
                vd[bt][jj] = *(const f32x4*)(vdot + (size_t)(bg * BPB + bL0 + bt) * JD
                                                   + (jq * 5 + jj) * OUT_DIM + dh * 4);
    }

    f32x4 sa[2][5];
    #pragma unroll
    for (int bt = 0; bt < 2; ++bt)
        #pragma unroll
        for (int jj = 0; jj < 5; ++jj) sa[bt][jj] = (f32x4){0.f, 0.f, 0.f, 0.f};

    for (int ch = 0; ch < 3; ++ch) {
        __syncthreads();
        // ---- stage W chunk: 24 i x 1280 floats = 7680 float4 ----
        {
            const f32x4* wg = (const f32x4*)(W + ((size_t)is * IPB + ch * CHUNK) * 1280);
            f32x4* wl4 = (f32x4*)wl;
            #pragma unroll
            for (int t = 0; t < 15; ++t)
                wl4[t * 512 + tid] = wg[t * 512 + tid];
        }
        __syncthreads();

        #pragma unroll
        for (int ip = 0; ip < 3; ++ip) {
            const int il = ig * 3 + ip;                 // i within chunk

            float xk[2][8];
            #pragma unroll
            for (int bt = 0; bt < 2; ++bt) {
                const f32x4* xr = (const f32x4*)(xs + (bL0 + bt) * XROW
                                                    + (ch * CHUNK + il) * 8);
                const f32x4 a0 = xr[0], a1 = xr[1];
                xk[bt][0]=a0.x; xk[bt][1]=a0.y; xk[bt][2]=a0.z; xk[bt][3]=a0.w;
                xk[bt][4]=a1.x; xk[bt][5]=a1.y; xk[bt][6]=a1.z; xk[bt][7]=a1.w;
            }

            f32x4 u[2][5];
            #pragma unroll
            for (int jj = 0; jj < 5; ++jj) {
                const f32x4* wp = (const f32x4*)(wl + il * 1280
                                                    + (jq * 5 + jj) * 128 + dh * 4);
                f32x4 a0 = (f32x4){0.f,0.f,0.f,0.f}, a1 = a0;
                #pragma unroll
                for (int k = 0; k < 8; ++k) {
                    const f32x4 w = wp[k * 4];
                    a0 += xk[0][k] * w;
                    a1 += xk[1][k] * w;
                }
                u[0][jj] = a0; u[1][jj] = a1;
            }

            if (PASS == 0) {
                #pragma unroll
                for (int bt = 0; bt < 2; ++bt)
                    #pragma unroll
                    for (int jj = 0; jj < 5; ++jj) sa[bt][jj] += 0.1f * u[bt][jj];
            } else {
                #pragma unroll
                for (int bt = 0; bt < 2; ++bt) {
                    float L[5];
                    #pragma unroll
                    for (int jj = 0; jj < 5; ++jj) {
                        const f32x4 p = vd[bt][jj] * u[bt][jj];
                        float t = (p.x + p.y) + (p.z + p.w);
                        t += __shfl_xor(t, 1);   // reduce over dh bit0
                        t += __shfl_xor(t, 2);   // reduce over dh bit1
                        L[jj] = t;
                    }
                    float m = fmaxf(fmaxf(fmaxf(L[0], L[1]), fmaxf(L[2], L[3])), L[4]);
                    m = fmaxf(m, __shfl_xor(m, 4));          // other j half
                    float e[5], Z = 0.f;
                    #pragma unroll
                    for (int jj = 0; jj < 5; ++jj) { e[jj] = __expf(L[jj] - m); Z += e[jj]; }
                    Z += __shfl_xor(Z, 4);
                    const float inv = 1.0f / Z;
                    #pragma unroll
                    for (int jj = 0; jj < 5; ++jj)
                        sa[bt][jj] += (e[jj] * inv) * u[bt][jj];
                }
            }
        }
    }

    // ---- reduce the 8 ig-partials through LDS (reuse wl), store slab ----
    __syncthreads();
    float* red = wl;
    #pragma unroll
    for (int bt = 0; bt < 2; ++bt)
        #pragma unroll
        for (int jj = 0; jj < 5; ++jj)
            *(f32x4*)(red + ig * REDSTRIDE
                          + ((bL0 + bt) * OUT_CAPS + (jq * 5 + jj)) * OUT_DIM + dh * 4)
                = sa[bt][jj];
    __syncthreads();
    {
        const size_t base = ((size_t)is * B_TOT + bg * BPB) * JD;
        #pragma unroll
        for (int r = 0; r < 5; ++r) {
            const int e = tid * 5 + r;       // 0..2559, exact coverage
            float acc = 0.f;
            #pragma unroll
            for (int p = 0; p < 8; ++p) acc += red[p * REDSTRIDE + e];
            s_part[base + e] = acc;
        }
    }
}

template<int PASS>
__global__ __launch_bounds__(256)
void caps_squash(const float* __restrict__ s_part,
                 float* __restrict__ vdot,
                 float* __restrict__ out) {
    const int e = blockIdx.x * 256 + threadIdx.x;   // < 40960
    float s = 0.f;
    #pragma unroll
    for (int p = 0; p < NSLICE; ++p)
        s += s_part[(size_t)p * (B_TOT * JD) + e];

    // squash over d: 16-lane butterfly (e%16 == lane%16)
    float t = s * s;
    t += __shfl_xor(t, 1);
    t += __shfl_xor(t, 2);
    t += __shfl_xor(t, 4);
    t += __shfl_xor(t, 8);
    const float scale = t / (1.0f + t) / sqrtf(t + 1e-7f);
    const float v = scale * s;

    if (PASS == 0)      vdot[e] = v;
    else if (PASS == 1) vdot[e] += v;
    else                out[e] = v;
}

// =====================================================================
// Fallback: round-1 fully fused kernel (only if ws_size too small)
// =====================================================================
#define FB_NGROUPS 32
#define FB_THREADS (FB_NGROUPS * OUT_DIM)
#define FB_ITERS (IN_CAPS / FB_NGROUPS)

__global__ __launch_bounds__(FB_THREADS)
void caps_routing_kernel(const float* __restrict__ x,
                         const float* __restrict__ W,
                         float* __restrict__ out) {
    __shared__ __align__(16) float xsf[IN_CAPS * 8];
    __shared__ float sredf[FB_NGROUPS * JD];
    __shared__ float vdot_lds[JD];

    const int b = blockIdx.x, tid = threadIdx.x;
    const int g = tid >> 4, d = tid & 15;
    {
        const float4* xg = reinterpret_cast<const float4*>(x + (size_t)b * IN_CAPS * 8);
        float4* xl = reinterpret_cast<float4*>(xsf);
        for (int t = tid; t < IN_CAPS * 2; t += FB_THREADS) xl[t] = xg[t];
    }
    __syncthreads();
    for (int pass = 0; pass < 3; ++pass) {
        float vdot_reg[OUT_CAPS];
        if (pass > 0) {
            #pragma unroll
            for (int j = 0; j < OUT_CAPS; ++j) vdot_reg[j] = vdot_lds[j * OUT_DIM + d];
        }
        float s_loc[OUT_CAPS];
        #pragma unroll
        for (int j = 0; j < OUT_CAPS; ++j) s_loc[j] = 0.f;
        for (int it = 0; it < FB_ITERS; ++it) {
            const int i = it * FB_NGROUPS + g;
            float xk[8];
            {
                const float4* xr = reinterpret_cast<const float4*>(xsf + i * 8);
                float4 a0 = xr[0], a1 = xr[1];
                xk[0]=a0.x; xk[1]=a0.y; xk[2]=a0.z; xk[3]=a0.w;
                xk[4]=a1.x; xk[5]=a1.y; xk[6]=a1.z; xk[7]=a1.w;
            }
            const float* wpf = W + (size_t)i * 1280 + d;
            float u[OUT_CAPS];
            #pragma unroll
            for (int j = 0; j < OUT_CAPS; ++j) {
                float acc = 0.f;
                #pragma unroll
                for (int k = 0; k < 8; ++k)
                    acc = fmaf(xk[k], wpf[j * 128 + k * OUT_DIM], acc);
                u[j] = acc;
            }
            if (pass == 0) {
                #pragma unroll
                for (int j = 0; j < OUT_CAPS; ++j) s_loc[j] = fmaf(0.1f, u[j], s_loc[j]);
            } else {
                float logit[OUT_CAPS];
                #pragma unroll
                for (int j = 0; j < OUT_CAPS; ++j) {
                    float t2 = vdot_reg[j] * u[j];
                    t2 += __shfl_xor(t2, 1); t2 += __shfl_xor(t2, 2);
                    t2 += __shfl_xor(t2, 4); t2 += __shfl_xor(t2, 8);
                    logit[j] = t2;
                }
                float m = logit[0];
                #pragma unroll
                for (int j = 1; j < OUT_CAPS; ++j) m = fmaxf(m, logit[j]);
                float Z = 0.f, e[OUT_CAPS];
                #pragma unroll
                for (int j = 0; j < OUT_CAPS; ++j) { e[j] = expf(logit[j] - m); Z += e[j]; }
                const float invZ = 1.0f / Z;
                #pragma unroll
                for (int j = 0; j < OUT_CAPS; ++j) s_loc[j] = fmaf(e[j] * invZ, u[j], s_loc[j]);
            }
        }
        #pragma unroll
        for (int j = 0; j < OUT_CAPS; ++j) sredf[g * JD + j * OUT_DIM + d] = s_loc[j];
        __syncthreads();
        if (tid < JD) {
            float sv = 0.f;
            #pragma unroll 8
            for (int gg = 0; gg < FB_NGROUPS; ++gg) sv += sredf[gg * JD + tid];
            float t2 = sv * sv;
            t2 += __shfl_xor(t2, 1); t2 += __shfl_xor(t2, 2);
            t2 += __shfl_xor(t2, 4); t2 += __shfl_xor(t2, 8);
            const float scale = t2 / (1.0f + t2) / sqrtf(t2 + 1e-7f);
            const float v = scale * sv;
            if (pass == 2) out[(size_t)b * JD + tid] = v;
            else vdot_lds[tid] = (pass == 0) ? v : (vdot_lds[tid] + v);
        }
        __syncthreads();
    }
}

extern "C" void kernel_launch(void* const* d_in, const int* in_sizes, int n_in,
                              void* d_out, int out_size, void* d_ws, size_t ws_size,
                              hipStream_t stream) {
    const float* x = (const float*)d_in[0];
    const float* W = (const float*)d_in[1];
    float* out = (float*)d_out;

    const size_t need = (SPART_ELEMS + VDOT_ELEMS) * sizeof(float);  // ~2.79 MB
    if (ws_size >= need) {
        float* s_part = (float*)d_ws;
        float* vdot   = (float*)d_ws + SPART_ELEMS;
        const dim3 gA(NSLICE, NBG);
        const int  gB = (B_TOT * JD) / 256;   // 160

        caps_main<0><<<gA, 512, 0, stream>>>(x, W, vdot, s_part);
        caps_squash<0><<<gB, 256, 0, stream>>>(s_part, vdot, out);
        caps_main<1><<<gA, 512, 0, stream>>>(x, W, vdot, s_part);
        caps_squash<1><<<gB, 256, 0, stream>>>(s_part, vdot, out);
        caps_main<2><<<gA, 512, 0, stream>>>(x, W, vdot, s_part);
        caps_squash<2><<<gB, 256, 0, stream>>>(s_part, vdot, out);
    } else {
        caps_routing_kernel<<<B_TOT, FB_THREADS, 0, stream>>>(x, W, out);
    }
}